// Round 1
// baseline (356.807 us; speedup 1.0000x reference)
//
#include <hip/hip_runtime.h>

// ---------------------------------------------------------------------------
// TransD-style scoring:
//   score[b] = || rp*(hp.h) + sum(h) + r - rp*(tp.t) - sum(t) ||^2
// Algebraic reduction: with a = hp.h - tp.t, c = sum(h) - sum(t):
//   score = a^2*S_pp + c^2*D + S_rr + 2ac*S_p + 2a*S_pr + 2c*S_r
// Per-node (sum, dot) precomputed in pass 1; per-relation sums in pass 2;
// O(1) scoring with L1/L2-resident gathers in pass 3.
// ---------------------------------------------------------------------------

#define ENT_DIM 128

// Pass 1: per-node (sum, dot) for head and tail tables.
// 8 rows per wave, 8 lanes per row, 4 float4 per lane per table.
// => 8 independent 16B loads in flight per lane (128 B/lane, 8 KB/wave),
//    3-stage xor reduce within aligned 8-lane groups.
// Each load instruction touches eight fully-consumed, 128B-aligned cache
// lines (rows are 512B-aligned; offsets are multiples of 128B).
__global__ void node_stats_kernel(const float* __restrict__ he,
                                  const float* __restrict__ hep,
                                  const float* __restrict__ te,
                                  const float* __restrict__ tep,
                                  float2* __restrict__ hstats,
                                  float2* __restrict__ tstats,
                                  int n_nodes) {
    const int wave = (blockIdx.x * blockDim.x + threadIdx.x) >> 6;
    const int lane = threadIdx.x & 63;
    const int sub  = lane >> 3;      // row slot within the wave: 0..7
    const int l    = lane & 7;       // float4 slot within the row: 0..7
    const int njobs = 2 * n_nodes;   // head rows then tail rows

    const int job = wave * 8 + sub;
    if (job >= njobs) return;

    const float* emb; const float* embp; float2* st; int node;
    if (job < n_nodes) { emb = he; embp = hep; st = hstats; node = job; }
    else               { emb = te; embp = tep; st = tstats; node = job - n_nodes; }

    const float4* vrow = (const float4*)(emb  + (size_t)node * ENT_DIM);
    const float4* prow = (const float4*)(embp + (size_t)node * ENT_DIM);

    // Batch all 8 loads before any consumption -> max memory-level parallelism.
    float4 v[4], p[4];
    #pragma unroll
    for (int k = 0; k < 4; ++k) v[k] = vrow[l + 8 * k];
    #pragma unroll
    for (int k = 0; k < 4; ++k) p[k] = prow[l + 8 * k];

    float s = 0.f, d = 0.f;
    #pragma unroll
    for (int k = 0; k < 4; ++k) {
        s += (v[k].x + v[k].y) + (v[k].z + v[k].w);
        d += v[k].x * p[k].x + v[k].y * p[k].y + v[k].z * p[k].z + v[k].w * p[k].w;
    }

    // Reduce across the 8 lanes of this row (xor masks 4,2,1 stay in-group).
    #pragma unroll
    for (int off = 4; off >= 1; off >>= 1) {
        s += __shfl_xor(s, off, 64);
        d += __shfl_xor(d, off, 64);
    }
    // Lanes 0,8,...,56 write 8 consecutive float2 (64B contiguous).
    if (l == 0) st[node] = make_float2(s, d);
}

// Pass 2: per-relation sums. One wave per relation (only 500 -> negligible).
__global__ void rel_stats_kernel(const float* __restrict__ re,
                                 const float* __restrict__ rep,
                                 float* __restrict__ rstats, int n_rels) {
    const int wave = (blockIdx.x * blockDim.x + threadIdx.x) >> 6;
    const int lane = threadIdx.x & 63;
    if (wave >= n_rels) return;

    const float2 r = ((const float2*)(re  + (size_t)wave * ENT_DIM))[lane];
    const float2 p = ((const float2*)(rep + (size_t)wave * ENT_DIM))[lane];
    float s_pp = p.x * p.x + p.y * p.y;
    float s_p  = p.x + p.y;
    float s_pr = p.x * r.x + p.y * r.y;
    float s_r  = r.x + r.y;
    float s_rr = r.x * r.x + r.y * r.y;
    #pragma unroll
    for (int off = 32; off >= 1; off >>= 1) {
        s_pp += __shfl_xor(s_pp, off, 64);
        s_p  += __shfl_xor(s_p,  off, 64);
        s_pr += __shfl_xor(s_pr, off, 64);
        s_r  += __shfl_xor(s_r,  off, 64);
        s_rr += __shfl_xor(s_rr, off, 64);
    }
    if (lane == 0) {
        float* o = rstats + (size_t)wave * 8;   // 32B stride per relation
        o[0] = s_pp; o[1] = s_p; o[2] = s_pr; o[3] = s_r; o[4] = s_rr;
    }
}

// Pass 3: one thread per batch element; all gathers hit L1/L2.
// rstats read vectorized: one float4 + one scalar instead of 5 scalar loads.
__global__ void score_kernel(const int* __restrict__ hidx,
                             const int* __restrict__ tidx,
                             const int* __restrict__ ridx,
                             const float2* __restrict__ hstats,
                             const float2* __restrict__ tstats,
                             const float* __restrict__ rstats,
                             float* __restrict__ out, int B) {
    const int b = blockIdx.x * blockDim.x + threadIdx.x;
    if (b >= B) return;
    const int hi = hidx[b], ti = tidx[b], ri = ridx[b];
    const float2 hs = hstats[hi];
    const float2 ts = tstats[ti];
    const float c = hs.x - ts.x;      // sum(h) - sum(t)
    const float a = hs.y - ts.y;      // (hp.h) - (tp.t)
    const float4 q0  = ((const float4*)rstats)[(size_t)ri * 2];  // s_pp,s_p,s_pr,s_r
    const float s_rr = rstats[(size_t)ri * 8 + 4];
    out[b] = a * a * q0.x + c * c * (float)ENT_DIM + s_rr
           + 2.0f * (a * c * q0.y + a * q0.z + c * q0.w);
}

// Fallback (only if ws_size is too small): direct wave-per-element compute.
__global__ void direct_kernel(const float* __restrict__ he, const float* __restrict__ hep,
                              const float* __restrict__ te, const float* __restrict__ tep,
                              const float* __restrict__ re, const float* __restrict__ rep,
                              const int* __restrict__ hidx, const int* __restrict__ tidx,
                              const int* __restrict__ ridx,
                              float* __restrict__ out, int B) {
    const int wave = (blockIdx.x * blockDim.x + threadIdx.x) >> 6;
    const int lane = threadIdx.x & 63;
    if (wave >= B) return;
    const int hi = hidx[wave], ti = tidx[wave], ri = ridx[wave];
    const float2 h  = ((const float2*)(he  + (size_t)hi * ENT_DIM))[lane];
    const float2 hp = ((const float2*)(hep + (size_t)hi * ENT_DIM))[lane];
    const float2 t  = ((const float2*)(te  + (size_t)ti * ENT_DIM))[lane];
    const float2 tp = ((const float2*)(tep + (size_t)ti * ENT_DIM))[lane];
    const float2 r  = ((const float2*)(re  + (size_t)ri * ENT_DIM))[lane];
    const float2 rp = ((const float2*)(rep + (size_t)ri * ENT_DIM))[lane];
    float hd = h.x * hp.x + h.y * hp.y;
    float hs = h.x + h.y;
    float td = t.x * tp.x + t.y * tp.y;
    float ts = t.x + t.y;
    #pragma unroll
    for (int off = 32; off >= 1; off >>= 1) {
        hd += __shfl_xor(hd, off, 64);
        hs += __shfl_xor(hs, off, 64);
        td += __shfl_xor(td, off, 64);
        ts += __shfl_xor(ts, off, 64);
    }
    const float a = hd - td, c = hs - ts;
    const float dx = a * rp.x + c + r.x;
    const float dy = a * rp.y + c + r.y;
    float sc = dx * dx + dy * dy;
    #pragma unroll
    for (int off = 32; off >= 1; off >>= 1) sc += __shfl_xor(sc, off, 64);
    if (lane == 0) out[wave] = sc;
}

extern "C" void kernel_launch(void* const* d_in, const int* in_sizes, int n_in,
                              void* d_out, int out_size, void* d_ws, size_t ws_size,
                              hipStream_t stream) {
    const float* he  = (const float*)d_in[0];
    const float* hep = (const float*)d_in[1];
    const float* te  = (const float*)d_in[2];
    const float* tep = (const float*)d_in[3];
    const float* re  = (const float*)d_in[4];
    const float* rep = (const float*)d_in[5];
    const int* hidx  = (const int*)d_in[6];
    const int* tidx  = (const int*)d_in[7];
    const int* ridx  = (const int*)d_in[8];
    float* out = (float*)d_out;

    const int n_nodes = in_sizes[0] / ENT_DIM;   // 200000
    const int n_rels  = in_sizes[4] / ENT_DIM;   // 500
    const int B       = in_sizes[6];             // 500000

    const size_t hstats_bytes = (size_t)n_nodes * sizeof(float2);
    const size_t rstats_bytes = (size_t)n_rels * 8 * sizeof(float);
    const size_t need = 2 * hstats_bytes + rstats_bytes;

    if (ws_size >= need) {
        float2* hstats = (float2*)d_ws;
        float2* tstats = (float2*)((char*)d_ws + hstats_bytes);
        float*  rstats = (float*)((char*)d_ws + 2 * hstats_bytes);

        // Pass 1: 2*n_nodes rows, 8 rows/wave, 4 waves/block.
        const int rows    = 2 * n_nodes;
        const int waves1  = (rows + 7) / 8;
        const int blocks1 = (waves1 + 3) / 4;
        node_stats_kernel<<<blocks1, 256, 0, stream>>>(he, hep, te, tep,
                                                       hstats, tstats, n_nodes);
        // Pass 2
        const int blocks2 = (n_rels * 64 + 255) / 256;
        rel_stats_kernel<<<blocks2, 256, 0, stream>>>(re, rep, rstats, n_rels);
        // Pass 3
        const int blocks3 = (B + 255) / 256;
        score_kernel<<<blocks3, 256, 0, stream>>>(hidx, tidx, ridx,
                                                  hstats, tstats, rstats, out, B);
    } else {
        const int blocks = (B * 64 + 255) / 256;
        direct_kernel<<<blocks, 256, 0, stream>>>(he, hep, te, tep, re, rep,
                                                  hidx, tidx, ridx, out, B);
    }
}

// Round 2
// 346.045 us; speedup vs baseline: 1.0311x; 1.0311x over previous
//
#include <hip/hip_runtime.h>

// ---------------------------------------------------------------------------
// TransD-style scoring:
//   score[b] = || rp*(hp.h) + sum(h) + r - rp*(tp.t) - sum(t) ||^2
// Algebraic reduction: with a = hp.h - tp.t, c = sum(h) - sum(t):
//   score = a^2*S_pp + c^2*D + S_rr + 2ac*S_p + 2a*S_pr + 2c*S_r
// Pass 1: per-node (sum, dot). Pass 2: per-relation sums. Pass 3: O(1) score.
// ---------------------------------------------------------------------------

#define ENT_DIM 128

// Pass 1: per-node (sum, dot) for head and tail tables.
// Round-0 structure (measured fastest): one wave handles 2 rows, lanes 0-31
// -> row 2w, lanes 32-63 -> row 2w+1. float4 loads, 2 contiguous 512B
// segments per instruction.
__global__ void node_stats_kernel(const float* __restrict__ he,
                                  const float* __restrict__ hep,
                                  const float* __restrict__ te,
                                  const float* __restrict__ tep,
                                  float2* __restrict__ hstats,
                                  float2* __restrict__ tstats,
                                  int n_nodes) {
    const int wave  = (blockIdx.x * blockDim.x + threadIdx.x) >> 6;
    const int lane  = threadIdx.x & 63;
    const int half  = lane >> 5;      // which of the 2 rows this lane serves
    const int l     = lane & 31;      // float4 index within the row
    const int njobs = 2 * n_nodes;    // head rows then tail rows

    int job = wave * 2 + half;
    if (job >= njobs) return;

    const float* emb; const float* embp; float2* st; int node;
    if (job < n_nodes) { emb = he; embp = hep; st = hstats; node = job; }
    else               { emb = te; embp = tep; st = tstats; node = job - n_nodes; }

    const float4 v  = ((const float4*)(emb  + (size_t)node * ENT_DIM))[l];
    const float4 vp = ((const float4*)(embp + (size_t)node * ENT_DIM))[l];
    float s = (v.x + v.y) + (v.z + v.w);
    float d = v.x * vp.x + v.y * vp.y + v.z * vp.z + v.w * vp.w;

    // reduce within each 32-lane half (xor masks < 32 never cross halves)
    #pragma unroll
    for (int off = 16; off >= 1; off >>= 1) {
        s += __shfl_xor(s, off, 64);
        d += __shfl_xor(d, off, 64);
    }
    if (l == 0) st[node] = make_float2(s, d);
}

// Pass 2: per-relation sums. One wave per relation (only 500).
__global__ void rel_stats_kernel(const float* __restrict__ re,
                                 const float* __restrict__ rep,
                                 float* __restrict__ rstats, int n_rels) {
    const int wave = (blockIdx.x * blockDim.x + threadIdx.x) >> 6;
    const int lane = threadIdx.x & 63;
    if (wave >= n_rels) return;

    const float2 r = ((const float2*)(re  + (size_t)wave * ENT_DIM))[lane];
    const float2 p = ((const float2*)(rep + (size_t)wave * ENT_DIM))[lane];
    float s_pp = p.x * p.x + p.y * p.y;
    float s_p  = p.x + p.y;
    float s_pr = p.x * r.x + p.y * r.y;
    float s_r  = r.x + r.y;
    float s_rr = r.x * r.x + r.y * r.y;
    #pragma unroll
    for (int off = 32; off >= 1; off >>= 1) {
        s_pp += __shfl_xor(s_pp, off, 64);
        s_p  += __shfl_xor(s_p,  off, 64);
        s_pr += __shfl_xor(s_pr, off, 64);
        s_r  += __shfl_xor(s_r,  off, 64);
        s_rr += __shfl_xor(s_rr, off, 64);
    }
    if (lane == 0) {
        float* o = rstats + (size_t)wave * 8;   // 32B stride per relation
        o[0] = s_pp; o[1] = s_p; o[2] = s_pr; o[3] = s_r; o[4] = s_rr;
    }
}

// Pass 3: 2 batch elements per thread.
//  - idx loads vectorized (int2, 8B/lane, coalesced)
//  - rstats staged in LDS with stride-9 padding: bank = (ri*9 + j) % 32
//    covers all 32 banks for random ri (stride-8 would hit only 4 banks)
//  - hstats/tstats gathers (L2-resident, 1.6MB each) issued back-to-back:
//    4 independent 8B gathers in flight per thread
__global__ void score_kernel(const int* __restrict__ hidx,
                             const int* __restrict__ tidx,
                             const int* __restrict__ ridx,
                             const float2* __restrict__ hstats,
                             const float2* __restrict__ tstats,
                             const float* __restrict__ rstats,
                             float* __restrict__ out, int B, int n_rels) {
    extern __shared__ float rs[];   // n_rels * 9 floats
    // Stage rstats (n_rels*8 floats, linear) -> LDS (stride 9).
    for (int i = threadIdx.x; i < n_rels * 2; i += blockDim.x) {
        const float4 v = ((const float4*)rstats)[i];
        const int base = (i >> 1) * 9 + (i & 1) * 4;
        rs[base]     = v.x;
        rs[base + 1] = v.y;
        rs[base + 2] = v.z;
        rs[base + 3] = v.w;
    }
    __syncthreads();

    const int g  = blockIdx.x * blockDim.x + threadIdx.x;
    const int b0 = 2 * g;
    if (b0 >= B) return;

    if (b0 + 1 < B) {
        const int2 hi = ((const int2*)hidx)[g];
        const int2 ti = ((const int2*)tidx)[g];
        const int2 ri = ((const int2*)ridx)[g];
        // issue all 4 gathers before consuming any
        const float2 hs0 = hstats[hi.x];
        const float2 hs1 = hstats[hi.y];
        const float2 ts0 = tstats[ti.x];
        const float2 ts1 = tstats[ti.y];

        const float c0 = hs0.x - ts0.x, a0 = hs0.y - ts0.y;
        const float c1 = hs1.x - ts1.x, a1 = hs1.y - ts1.y;
        const float* q0 = rs + ri.x * 9;
        const float* q1 = rs + ri.y * 9;
        const float sc0 = a0 * a0 * q0[0] + c0 * c0 * (float)ENT_DIM + q0[4]
                        + 2.0f * (a0 * c0 * q0[1] + a0 * q0[2] + c0 * q0[3]);
        const float sc1 = a1 * a1 * q1[0] + c1 * c1 * (float)ENT_DIM + q1[4]
                        + 2.0f * (a1 * c1 * q1[1] + a1 * q1[2] + c1 * q1[3]);
        ((float2*)out)[g] = make_float2(sc0, sc1);
    } else {
        // tail element (only if B is odd)
        const int hi = hidx[b0], ti = tidx[b0], ri = ridx[b0];
        const float2 hs = hstats[hi];
        const float2 ts = tstats[ti];
        const float c = hs.x - ts.x, a = hs.y - ts.y;
        const float* q = rs + ri * 9;
        out[b0] = a * a * q[0] + c * c * (float)ENT_DIM + q[4]
                + 2.0f * (a * c * q[1] + a * q[2] + c * q[3]);
    }
}

// Fallback (only if ws_size is too small): direct wave-per-element compute.
__global__ void direct_kernel(const float* __restrict__ he, const float* __restrict__ hep,
                              const float* __restrict__ te, const float* __restrict__ tep,
                              const float* __restrict__ re, const float* __restrict__ rep,
                              const int* __restrict__ hidx, const int* __restrict__ tidx,
                              const int* __restrict__ ridx,
                              float* __restrict__ out, int B) {
    const int wave = (blockIdx.x * blockDim.x + threadIdx.x) >> 6;
    const int lane = threadIdx.x & 63;
    if (wave >= B) return;
    const int hi = hidx[wave], ti = tidx[wave], ri = ridx[wave];
    const float2 h  = ((const float2*)(he  + (size_t)hi * ENT_DIM))[lane];
    const float2 hp = ((const float2*)(hep + (size_t)hi * ENT_DIM))[lane];
    const float2 t  = ((const float2*)(te  + (size_t)ti * ENT_DIM))[lane];
    const float2 tp = ((const float2*)(tep + (size_t)ti * ENT_DIM))[lane];
    const float2 r  = ((const float2*)(re  + (size_t)ri * ENT_DIM))[lane];
    const float2 rp = ((const float2*)(rep + (size_t)ri * ENT_DIM))[lane];
    float hd = h.x * hp.x + h.y * hp.y;
    float hs = h.x + h.y;
    float td = t.x * tp.x + t.y * tp.y;
    float ts = t.x + t.y;
    #pragma unroll
    for (int off = 32; off >= 1; off >>= 1) {
        hd += __shfl_xor(hd, off, 64);
        hs += __shfl_xor(hs, off, 64);
        td += __shfl_xor(td, off, 64);
        ts += __shfl_xor(ts, off, 64);
    }
    const float a = hd - td, c = hs - ts;
    const float dx = a * rp.x + c + r.x;
    const float dy = a * rp.y + c + r.y;
    float sc = dx * dx + dy * dy;
    #pragma unroll
    for (int off = 32; off >= 1; off >>= 1) sc += __shfl_xor(sc, off, 64);
    if (lane == 0) out[wave] = sc;
}

extern "C" void kernel_launch(void* const* d_in, const int* in_sizes, int n_in,
                              void* d_out, int out_size, void* d_ws, size_t ws_size,
                              hipStream_t stream) {
    const float* he  = (const float*)d_in[0];
    const float* hep = (const float*)d_in[1];
    const float* te  = (const float*)d_in[2];
    const float* tep = (const float*)d_in[3];
    const float* re  = (const float*)d_in[4];
    const float* rep = (const float*)d_in[5];
    const int* hidx  = (const int*)d_in[6];
    const int* tidx  = (const int*)d_in[7];
    const int* ridx  = (const int*)d_in[8];
    float* out = (float*)d_out;

    const int n_nodes = in_sizes[0] / ENT_DIM;   // 200000
    const int n_rels  = in_sizes[4] / ENT_DIM;   // 500
    const int B       = in_sizes[6];             // 500000

    const size_t hstats_bytes = (size_t)n_nodes * sizeof(float2);
    const size_t rstats_bytes = (size_t)n_rels * 8 * sizeof(float);
    const size_t need = 2 * hstats_bytes + rstats_bytes;
    const size_t lds_bytes = (size_t)n_rels * 9 * sizeof(float);

    if (ws_size >= need && lds_bytes <= 60 * 1024) {
        float2* hstats = (float2*)d_ws;
        float2* tstats = (float2*)((char*)d_ws + hstats_bytes);
        float*  rstats = (float*)((char*)d_ws + 2 * hstats_bytes);

        // Pass 1: 2*n_nodes rows, 2 rows/wave, 4 waves/block.
        const int waves1  = n_nodes;                  // (2*n_nodes jobs)/2
        const int blocks1 = (waves1 + 3) / 4;
        node_stats_kernel<<<blocks1, 256, 0, stream>>>(he, hep, te, tep,
                                                       hstats, tstats, n_nodes);
        // Pass 2
        const int blocks2 = (n_rels * 64 + 255) / 256;
        rel_stats_kernel<<<blocks2, 256, 0, stream>>>(re, rep, rstats, n_rels);
        // Pass 3: 2 elements per thread.
        const int nthreads = (B + 1) / 2;
        const int blocks3  = (nthreads + 255) / 256;
        score_kernel<<<blocks3, 256, lds_bytes, stream>>>(hidx, tidx, ridx,
                                                          hstats, tstats, rstats,
                                                          out, B, n_rels);
    } else {
        const int blocks = (B * 64 + 255) / 256;
        direct_kernel<<<blocks, 256, 0, stream>>>(he, hep, te, tep, re, rep,
                                                  hidx, tidx, ridx, out, B);
    }
}